// Round 1
// baseline (11023.618 us; speedup 1.0000x reference)
//
#include <hip/hip_runtime.h>
#include <hip/hip_bf16.h>
#include <stdint.h>

#define B_  256
#define T_  512
#define H_  1024
#define KD  1024
#define BH  (B_ * H_)

typedef float  f32x4  __attribute__((ext_vector_type(4)));
typedef float  f32x16 __attribute__((ext_vector_type(16)));
typedef __bf16 bf16x8 __attribute__((ext_vector_type(8)));

__device__ inline ushort f2bf(float f) {
  union { float f; uint32_t u; } v; v.f = f;
  uint32_t u = v.u;
  return (ushort)((u + 0x7fffu + ((u >> 16) & 1u)) >> 16);   // RNE
}
__device__ inline float bf2f(ushort h) {
  union { uint32_t u; float f; } v; v.u = ((uint32_t)h) << 16;
  return v.f;
}
__device__ inline bf16x8 ld_bf8(const ushort* p) {
  union { uint4 u; bf16x8 b; } v;
  v.u = *(const uint4*)p;
  return v.b;
}
__device__ inline float tanh_fast(float x) {
  float xc = fminf(fmaxf(x, -15.f), 15.f);
  float e  = __expf(2.f * xc);
  return (e - 1.f) * __builtin_amdgcn_rcpf(e + 1.f);
}

// ---------------------------------------------------------------- Wh -> bf16
__global__ __launch_bounds__(256) void wh_convert(const float* __restrict__ W,
                                                  ushort* __restrict__ whb) {
  int gid = blockIdx.x * 256 + threadIdx.x;       // 131072 threads, 8 elems each
  int row = gid >> 7;
  int kg  = (gid & 127) << 3;
  const float* s = W + (size_t)row * 2048 + 1024 + kg;   // Wh = W[:, 1024:]
  float4 f0 = *(const float4*)s;
  float4 f1 = *(const float4*)(s + 4);
  ushort o[8] = { f2bf(f0.x), f2bf(f0.y), f2bf(f0.z), f2bf(f0.w),
                  f2bf(f1.x), f2bf(f1.y), f2bf(f1.z), f2bf(f1.w) };
  *(uint4*)(whb + (size_t)row * 1024 + kg) = *(const uint4*)o;
}

// ------------------------------------------------- x_proj = xs @ Wx^T + bias
// C (BT x H) tiled 128x128, BK=32, 4 waves (2x2), wave = 64x64 (4x4 frags of
// 16x16x32 bf16 MFMA). A (xs) is fp32 -> converted during reg-staged LDS fill.
// Output written bf16 in (T, B, H) layout so the scan's step slice is dense.
__global__ __launch_bounds__(256) void xproj_gemm(const float* __restrict__ xs,
                                                  const float* __restrict__ W,
                                                  const float* __restrict__ bias,
                                                  ushort* __restrict__ xp) {
  __shared__ ushort As[128 * 32];
  __shared__ ushort Bs[128 * 32];
  const int bid = blockIdx.x;
  const int mt = bid & 1023, nt = bid >> 10;   // consecutive bids -> new A panel
  const int tid = threadIdx.x;
  const int lane = tid & 63, wid = tid >> 6;
  const int wr = wid >> 1, wc = wid & 1;
  const int lr = lane & 15, lq = lane >> 4;

  const int srow = tid >> 1, scol = (tid & 1) * 16;
  const float* ag = xs + (size_t)(mt * 128 + srow) * 1024 + scol;
  const float* bg = W  + (size_t)(nt * 128 + srow) * 2048 + scol;  // Wx cols
  ushort* as = As + srow * 32 + scol;
  ushort* bs = Bs + srow * 32 + scol;

  f32x4 acc[4][4];
#pragma unroll
  for (int m = 0; m < 4; ++m)
#pragma unroll
    for (int n = 0; n < 4; ++n) acc[m][n] = (f32x4){0.f, 0.f, 0.f, 0.f};

  for (int kc = 0; kc < 32; ++kc) {
    float4 a0 = *(const float4*)(ag + kc * 32);
    float4 a1 = *(const float4*)(ag + kc * 32 + 4);
    float4 a2 = *(const float4*)(ag + kc * 32 + 8);
    float4 a3 = *(const float4*)(ag + kc * 32 + 12);
    float4 b0 = *(const float4*)(bg + kc * 32);
    float4 b1 = *(const float4*)(bg + kc * 32 + 4);
    float4 b2 = *(const float4*)(bg + kc * 32 + 8);
    float4 b3 = *(const float4*)(bg + kc * 32 + 12);
    __syncthreads();
    {
      ushort t[16] = { f2bf(a0.x), f2bf(a0.y), f2bf(a0.z), f2bf(a0.w),
                       f2bf(a1.x), f2bf(a1.y), f2bf(a1.z), f2bf(a1.w),
                       f2bf(a2.x), f2bf(a2.y), f2bf(a2.z), f2bf(a2.w),
                       f2bf(a3.x), f2bf(a3.y), f2bf(a3.z), f2bf(a3.w) };
      *(uint4*)as       = *(const uint4*)t;
      *(uint4*)(as + 8) = *(const uint4*)(t + 8);
      ushort u[16] = { f2bf(b0.x), f2bf(b0.y), f2bf(b0.z), f2bf(b0.w),
                       f2bf(b1.x), f2bf(b1.y), f2bf(b1.z), f2bf(b1.w),
                       f2bf(b2.x), f2bf(b2.y), f2bf(b2.z), f2bf(b2.w),
                       f2bf(b3.x), f2bf(b3.y), f2bf(b3.z), f2bf(b3.w) };
      *(uint4*)bs       = *(const uint4*)u;
      *(uint4*)(bs + 8) = *(const uint4*)(u + 8);
    }
    __syncthreads();
    bf16x8 af[4], bf[4];
#pragma unroll
    for (int m = 0; m < 4; ++m)
      af[m] = ld_bf8(As + (wr * 64 + m * 16 + lr) * 32 + lq * 8);
#pragma unroll
    for (int n = 0; n < 4; ++n)
      bf[n] = ld_bf8(Bs + (wc * 64 + n * 16 + lr) * 32 + lq * 8);
#pragma unroll
    for (int m = 0; m < 4; ++m)
#pragma unroll
      for (int n = 0; n < 4; ++n)
        acc[m][n] = __builtin_amdgcn_mfma_f32_16x16x32_bf16(af[m], bf[n], acc[m][n], 0, 0, 0);
  }

  // epilogue: C/D layout col = lane&15, row = lq*4 + reg (m89-verified)
#pragma unroll
  for (int n = 0; n < 4; ++n) {
    int gn = nt * 128 + wc * 64 + n * 16 + lr;
    float bv = bias[gn];
#pragma unroll
    for (int m = 0; m < 4; ++m) {
      int gmb = mt * 128 + wr * 64 + m * 16 + lq * 4;
#pragma unroll
      for (int r = 0; r < 4; ++r) {
        int gm = gmb + r;
        int bi = gm >> 9, ti = gm & 511;     // m = b*512 + t
        xp[((size_t)ti * B_ + bi) * H_ + gn] = f2bf(acc[m][n][r] + bv);
      }
    }
  }
}

// ------------------------------------------------------ software grid barrier
__device__ inline void gbar(int* flags, int* go, int step, int bid, int tid) {
  __syncthreads();
  if (tid == 0) {
    __threadfence();  // release: flush h stores to device coherence point
    __hip_atomic_store(flags + bid * 32, step, __ATOMIC_RELAXED, __HIP_MEMORY_SCOPE_AGENT);
  }
  if (bid == 0) {
    if (tid < 64) {
      while (__hip_atomic_load(flags + tid * 32, __ATOMIC_RELAXED, __HIP_MEMORY_SCOPE_AGENT) < step) {}
    }
    __syncthreads();
    if (tid == 0)
      __hip_atomic_store(go, step, __ATOMIC_RELAXED, __HIP_MEMORY_SCOPE_AGENT);
  }
  if (tid == 0) {
    while (__hip_atomic_load(go, __ATOMIC_RELAXED, __HIP_MEMORY_SCOPE_AGENT) < step) {}
    __threadfence();  // acquire: invalidate caches before reading peers' h
  }
  __syncthreads();
}

// ----------------------------------------------------------- persistent scan
// 64 wgs (guaranteed co-resident on 256 CUs), 4 waves each, no LDS.
// wg tile 64(batch) x 64(H); wave = one 32x32 tile via mfma_f32_32x32x16_bf16.
// A (h) and B (Wh) fragments loaded directly from L2-resident global bf16.
__global__ __launch_bounds__(256) void rnn_scan(const ushort* __restrict__ xp,
                                                const ushort* __restrict__ whb,
                                                ushort* __restrict__ hb,
                                                float* __restrict__ out,
                                                int* __restrict__ flags,
                                                int* __restrict__ go) {
  const int bid = blockIdx.x, tid = threadIdx.x;
  const int lane = tid & 63, wid = tid >> 6;
  const int mt = bid & 3, nt = bid >> 2;          // 4 x 16 tiles
  const int wr = wid >> 1, wc = wid & 1;
  const int l31 = lane & 31, l5 = lane >> 5;

  const int brow_base = mt * 64 + wr * 32;
  const int ncol = nt * 64 + wc * 32 + l31;       // C col == Wh row
  const int arow = brow_base + l31;               // A row (h batch index)
  const ushort* bsrc = whb + (size_t)ncol * 1024 + l5 * 8;

  // C/D mapping (m74/m101): col = lane&31, row = (r&3) + 8*(r>>2) + 4*(lane>>5)
  int crow[16];
#pragma unroll
  for (int r = 0; r < 16; ++r) crow[r] = brow_base + (r & 3) + 8 * (r >> 2) + 4 * l5;

  // ---- step 0: h1 = tanh(xp[0])  (h0 == 0)
  {
#pragma unroll
    for (int r = 0; r < 16; ++r) {
      float v = tanh_fast(bf2f(xp[(size_t)crow[r] * H_ + ncol]));
      hb[(size_t)crow[r] * H_ + ncol] = f2bf(v);
    }
  }
  gbar(flags, go, 1, bid, tid);

  for (int s = 1; s < T_; ++s) {
    const ushort* hprev = hb + ((s + 1) & 1) * BH;
    ushort*       hnext = hb + (s & 1) * BH;
    const ushort* asrc = hprev + (size_t)arow * 1024 + l5 * 8;

    f32x16 acc;
#pragma unroll
    for (int i = 0; i < 16; ++i) acc[i] = 0.f;

#pragma unroll 8
    for (int kc = 0; kc < 64; ++kc) {           // K = 1024 in steps of 16
      bf16x8 av = ld_bf8(asrc + kc * 16);
      bf16x8 bv = ld_bf8(bsrc + kc * 16);
      acc = __builtin_amdgcn_mfma_f32_32x32x16_bf16(av, bv, acc, 0, 0, 0);
    }

    const ushort* xrow = xp + (size_t)s * BH;
    if (s < T_ - 1) {
#pragma unroll
      for (int r = 0; r < 16; ++r) {
        float v = tanh_fast(acc[r] + bf2f(xrow[(size_t)crow[r] * H_ + ncol]));
        hnext[(size_t)crow[r] * H_ + ncol] = f2bf(v);
      }
      gbar(flags, go, s + 1, bid, tid);
    } else {
#pragma unroll
      for (int r = 0; r < 16; ++r) {
        float v = tanh_fast(acc[r] + bf2f(xrow[(size_t)crow[r] * H_ + ncol]));
        out[(size_t)crow[r] * H_ + ncol] = v;
        out[(size_t)BH + (size_t)crow[r] * H_ + ncol] = v;
      }
    }
  }
}

// ---------------------------------------------------------------------- host
extern "C" void kernel_launch(void* const* d_in, const int* in_sizes, int n_in,
                              void* d_out, int out_size, void* d_ws, size_t ws_size,
                              hipStream_t stream) {
  const float* xs   = (const float*)d_in[0];
  const float* W    = (const float*)d_in[1];
  const float* bias = (const float*)d_in[2];
  float* out = (float*)d_out;
  char*  ws  = (char*)d_ws;

  const size_t XP_OFF = 0;                       // bf16 x_proj (T,B,H): 256 MiB
  const size_t WH_OFF = 268435456;               // bf16 Wh (H,H):        2 MiB
  const size_t HB_OFF = WH_OFF + 2097152;        // bf16 h double-buffer: 1 MiB
  const size_t BR_OFF = HB_OFF + 1048576;        // barrier flags
  const size_t NEED   = BR_OFF + 16384;
  if (ws_size < NEED) {                          // defensive: avoid OOB scribble
    hipMemsetAsync(d_out, 0, (size_t)out_size * 4, stream);
    return;
  }

  ushort* xp    = (ushort*)(ws + XP_OFF);
  ushort* whb   = (ushort*)(ws + WH_OFF);
  ushort* hb    = (ushort*)(ws + HB_OFF);
  int*    flags = (int*)(ws + BR_OFF);
  int*    go    = flags + 64 * 32;

  // barrier state must be fresh every call (ws not re-poisoned between replays)
  hipMemsetAsync(flags, 0, (64 * 32 + 32) * sizeof(int), stream);

  wh_convert<<<512, 256, 0, stream>>>(W, whb);
  xproj_gemm<<<8192, 256, 0, stream>>>(xs, W, bias, xp);
  rnn_scan<<<64, 256, 0, stream>>>(xp, whb, hb, out, flags, go);
}

// Round 2
// 5782.853 us; speedup vs baseline: 1.9063x; 1.9063x over previous
//
#include <hip/hip_runtime.h>
#include <hip/hip_bf16.h>
#include <stdint.h>

#define B_  256
#define T_  512
#define H_  1024
#define BH  (B_ * H_)

typedef float  f32x4  __attribute__((ext_vector_type(4)));
typedef __bf16 bf16x8 __attribute__((ext_vector_type(8)));
typedef unsigned long long u64;

__device__ inline ushort f2bf(float f) {
  union { float f; uint32_t u; } v; v.f = f;
  uint32_t u = v.u;
  return (ushort)((u + 0x7fffu + ((u >> 16) & 1u)) >> 16);   // RNE
}
__device__ inline float bf2f(ushort h) {
  union { uint32_t u; float f; } v; v.u = ((uint32_t)h) << 16;
  return v.f;
}
__device__ inline bf16x8 ld_bf8(const ushort* p) {
  union { uint4 u; bf16x8 b; } v;
  v.u = *(const uint4*)p;
  return v.b;
}
// device-scope (cross-XCD coherent) 16B load as two tracked 8B atomic loads
__device__ inline bf16x8 ld_bf8_coh(const ushort* p) {
  union { u64 q[2]; bf16x8 b; } v;
  v.q[0] = __hip_atomic_load((const u64*)p,       __ATOMIC_RELAXED, __HIP_MEMORY_SCOPE_AGENT);
  v.q[1] = __hip_atomic_load(((const u64*)p) + 1, __ATOMIC_RELAXED, __HIP_MEMORY_SCOPE_AGENT);
  return v.b;
}
// device-scope 2B store (bypasses L1/L2 to the coherence point)
__device__ inline void st_bf_coh(ushort* p, ushort v) {
  asm volatile("global_store_short %0, %1, off sc1" :: "v"(p), "v"((uint32_t)v) : "memory");
}
__device__ inline float tanh_fast(float x) {
  float xc = fminf(fmaxf(x, -15.f), 15.f);
  float e  = __expf(2.f * xc);
  return (e - 1.f) * __builtin_amdgcn_rcpf(e + 1.f);
}

// ------------------------------------------------- x_proj = xs @ Wx^T + bias
// (unchanged from r1 — passed). Output bf16 in (T, B, H) layout.
__global__ __launch_bounds__(256) void xproj_gemm(const float* __restrict__ xs,
                                                  const float* __restrict__ W,
                                                  const float* __restrict__ bias,
                                                  ushort* __restrict__ xp) {
  __shared__ ushort As[128 * 32];
  __shared__ ushort Bs[128 * 32];
  const int bid = blockIdx.x;
  const int mt = bid & 1023, nt = bid >> 10;
  const int tid = threadIdx.x;
  const int lane = tid & 63, wid = tid >> 6;
  const int wr = wid >> 1, wc = wid & 1;
  const int lr = lane & 15, lq = lane >> 4;

  const int srow = tid >> 1, scol = (tid & 1) * 16;
  const float* ag = xs + (size_t)(mt * 128 + srow) * 1024 + scol;
  const float* bg = W  + (size_t)(nt * 128 + srow) * 2048 + scol;
  ushort* as = As + srow * 32 + scol;
  ushort* bs = Bs + srow * 32 + scol;

  f32x4 acc[4][4];
#pragma unroll
  for (int m = 0; m < 4; ++m)
#pragma unroll
    for (int n = 0; n < 4; ++n) acc[m][n] = (f32x4){0.f, 0.f, 0.f, 0.f};

  for (int kc = 0; kc < 32; ++kc) {
    float4 a0 = *(const float4*)(ag + kc * 32);
    float4 a1 = *(const float4*)(ag + kc * 32 + 4);
    float4 a2 = *(const float4*)(ag + kc * 32 + 8);
    float4 a3 = *(const float4*)(ag + kc * 32 + 12);
    float4 b0 = *(const float4*)(bg + kc * 32);
    float4 b1 = *(const float4*)(bg + kc * 32 + 4);
    float4 b2 = *(const float4*)(bg + kc * 32 + 8);
    float4 b3 = *(const float4*)(bg + kc * 32 + 12);
    __syncthreads();
    {
      ushort t[16] = { f2bf(a0.x), f2bf(a0.y), f2bf(a0.z), f2bf(a0.w),
                       f2bf(a1.x), f2bf(a1.y), f2bf(a1.z), f2bf(a1.w),
                       f2bf(a2.x), f2bf(a2.y), f2bf(a2.z), f2bf(a2.w),
                       f2bf(a3.x), f2bf(a3.y), f2bf(a3.z), f2bf(a3.w) };
      *(uint4*)as       = *(const uint4*)t;
      *(uint4*)(as + 8) = *(const uint4*)(t + 8);
      ushort u[16] = { f2bf(b0.x), f2bf(b0.y), f2bf(b0.z), f2bf(b0.w),
                       f2bf(b1.x), f2bf(b1.y), f2bf(b1.z), f2bf(b1.w),
                       f2bf(b2.x), f2bf(b2.y), f2bf(b2.z), f2bf(b2.w),
                       f2bf(b3.x), f2bf(b3.y), f2bf(b3.z), f2bf(b3.w) };
      *(uint4*)bs       = *(const uint4*)u;
      *(uint4*)(bs + 8) = *(const uint4*)(u + 8);
    }
    __syncthreads();
    bf16x8 af[4], bfv[4];
#pragma unroll
    for (int m = 0; m < 4; ++m)
      af[m] = ld_bf8(As + (wr * 64 + m * 16 + lr) * 32 + lq * 8);
#pragma unroll
    for (int n = 0; n < 4; ++n)
      bfv[n] = ld_bf8(Bs + (wc * 64 + n * 16 + lr) * 32 + lq * 8);
#pragma unroll
    for (int m = 0; m < 4; ++m)
#pragma unroll
      for (int n = 0; n < 4; ++n)
        acc[m][n] = __builtin_amdgcn_mfma_f32_16x16x32_bf16(af[m], bfv[n], acc[m][n], 0, 0, 0);
  }

#pragma unroll
  for (int n = 0; n < 4; ++n) {
    int gn = nt * 128 + wc * 64 + n * 16 + lr;
    float bv = bias[gn];
#pragma unroll
    for (int m = 0; m < 4; ++m) {
      int gmb = mt * 128 + wr * 64 + m * 16 + lq * 4;
#pragma unroll
      for (int r = 0; r < 4; ++r) {
        int gm = gmb + r;
        int bi = gm >> 9, ti = gm & 511;     // m = b*512 + t
        xp[((size_t)ti * B_ + bi) * H_ + gn] = f2bf(acc[m][n][r] + bv);
      }
    }
  }
}

// ---------------------------------------- one-hop all-to-all software barrier
// release: drain this wave's vmem (incl. asm sc1 stores) + wg barrier, then
// post flag (agent atomic, sc1). acquire: poll all 128 flags (agent atomics,
// coherence point) — no cache invalidation needed since h I/O is sc1.
__device__ inline void gbar(int* flags, int step, int bid, int tid) {
  asm volatile("s_waitcnt vmcnt(0)" ::: "memory");
  __syncthreads();
  if (tid == 0)
    __hip_atomic_store(flags + bid * 16, step, __ATOMIC_RELAXED, __HIP_MEMORY_SCOPE_AGENT);
  if (tid < 128) {
    while (__hip_atomic_load(flags + tid * 16, __ATOMIC_RELAXED, __HIP_MEMORY_SCOPE_AGENT) < step) {}
  }
  __syncthreads();
}

// ----------------------------------------------------------- persistent scan
// 128 wgs x 256 thr (4 waves). wg tile = 64 batch-rows x 32 H-cols.
// Wave = 16 rows x 32 cols (2 x 16x16x32 MFMA chains). Wh col-slice lives in
// LDS (staged once, XOR-swizzled). h exchanged via sc1 (device-scope) ops.
__global__ __launch_bounds__(256) void rnn_scan(const float* __restrict__ W,
                                                const ushort* __restrict__ xp,
                                                ushort* __restrict__ hb,
                                                float* __restrict__ out,
                                                int* __restrict__ flags) {
  __shared__ ushort Bsm[32 * 1024];          // 64 KB: Wh cols [ct*32, +32)
  const int bid = blockIdx.x, tid = threadIdx.x;
  const int rt = bid & 3, ct = bid >> 2;     // 4 row-tiles x 32 col-tiles
  const int lane = tid & 63, wid = tid >> 6;
  const int lr = lane & 15, lq = lane >> 4;
  const int rbase = rt * 64 + wid * 16;

  // ---- one-time stage: Wh (fp32, W[:,1024:]) -> bf16 LDS, 16B-granule swizzle
  {
    const int c  = tid >> 3;                 // 0..31  (local col)
    const int qb = (tid & 7) * 16;           // 16 x 16B chunks per thread
    const float* src = W + (size_t)(ct * 32 + c) * 2048 + 1024;
    char* dst = (char*)Bsm + c * 2048;
    const int sw = (c & 7) << 4;
#pragma unroll
    for (int q = qb; q < qb + 16; ++q) {
      float4 f0 = *(const float4*)(src + q * 8);
      float4 f1 = *(const float4*)(src + q * 8 + 4);
      ushort t[8] = { f2bf(f0.x), f2bf(f0.y), f2bf(f0.z), f2bf(f0.w),
                      f2bf(f1.x), f2bf(f1.y), f2bf(f1.z), f2bf(f1.w) };
      *(uint4*)(dst + ((q * 16) ^ sw)) = *(const uint4*)t;
    }
  }
  __syncthreads();

  const int gc0 = ct * 32 + lr;              // global col of frag 0 (frag1: +16)
  const int swz = (lr & 7) << 4;
  const int kb  = lq * 16;                   // lane's k-subgroup byte offset
  const char* bp0 = (char*)Bsm + lr * 2048;
  const char* bp1 = (char*)Bsm + (16 + lr) * 2048;

  // ---- step 0: h1 = tanh(xp[0])   (h0 == 0)
#pragma unroll
  for (int r = 0; r < 4; ++r) {
    int gr = rbase + lq * 4 + r;
    float v0 = tanh_fast(bf2f(xp[(size_t)gr * H_ + gc0]));
    float v1 = tanh_fast(bf2f(xp[(size_t)gr * H_ + gc0 + 16]));
    st_bf_coh(hb + (size_t)gr * H_ + gc0,      f2bf(v0));
    st_bf_coh(hb + (size_t)gr * H_ + gc0 + 16, f2bf(v1));
  }
  gbar(flags, 1, bid, tid);

#define LOADG(A, g) \
  _Pragma("unroll") for (int j = 0; j < 8; ++j) A[j] = ld_bf8_coh(arow + ((g) * 8 + j) * 32);
#define COMPG(A, g) \
  _Pragma("unroll") for (int j = 0; j < 8; ++j) { \
    const int off = (((((g) * 8 + j)) << 6) | kb) ^ swz; \
    bf16x8 b0 = *(const bf16x8*)(bp0 + off); \
    bf16x8 b1 = *(const bf16x8*)(bp1 + off); \
    acc0 = __builtin_amdgcn_mfma_f32_16x16x32_bf16(A[j], b0, acc0, 0, 0, 0); \
    acc1 = __builtin_amdgcn_mfma_f32_16x16x32_bf16(A[j], b1, acc1, 0, 0, 0); }

  for (int s = 1; s < T_; ++s) {
    const ushort* hprev = hb + ((s + 1) & 1) * BH;
    ushort*       hnext = hb + (s & 1) * BH;
    const ushort* xrow  = xp + (size_t)s * BH;

    // prefetch this step's xp slice (normal cached loads; hides HBM latency)
    ushort xv[8];
#pragma unroll
    for (int r = 0; r < 4; ++r) {
      int gr = rbase + lq * 4 + r;
      xv[r]     = xrow[(size_t)gr * H_ + gc0];
      xv[r + 4] = xrow[(size_t)gr * H_ + gc0 + 16];
    }

    const ushort* arow = hprev + (size_t)(rbase + lr) * H_ + lq * 8;
    f32x4 acc0 = {0.f, 0.f, 0.f, 0.f}, acc1 = {0.f, 0.f, 0.f, 0.f};

    // hand-pipelined: >=8 coherent A-loads in flight while MFMAs run
    bf16x8 a0[8], a1[8];
    LOADG(a0, 0)
    LOADG(a1, 1)
    COMPG(a0, 0)
    LOADG(a0, 2)
    COMPG(a1, 1)
    LOADG(a1, 3)
    COMPG(a0, 2)
    COMPG(a1, 3)

    if (s < T_ - 1) {
#pragma unroll
      for (int r = 0; r < 4; ++r) {
        int gr = rbase + lq * 4 + r;
        float v0 = tanh_fast(acc0[r] + bf2f(xv[r]));
        float v1 = tanh_fast(acc1[r] + bf2f(xv[r + 4]));
        st_bf_coh(hnext + (size_t)gr * H_ + gc0,      f2bf(v0));
        st_bf_coh(hnext + (size_t)gr * H_ + gc0 + 16, f2bf(v1));
      }
      gbar(flags, s + 1, bid, tid);
    } else {
#pragma unroll
      for (int r = 0; r < 4; ++r) {
        int gr = rbase + lq * 4 + r;
        float v0 = tanh_fast(acc0[r] + bf2f(xv[r]));
        float v1 = tanh_fast(acc1[r] + bf2f(xv[r + 4]));
        out[(size_t)gr * H_ + gc0]                   = v0;
        out[(size_t)gr * H_ + gc0 + 16]              = v1;
        out[(size_t)BH + (size_t)gr * H_ + gc0]      = v0;
        out[(size_t)BH + (size_t)gr * H_ + gc0 + 16] = v1;
      }
    }
  }
#undef LOADG
#undef COMPG
}

// ---------------------------------------------------------------------- host
extern "C" void kernel_launch(void* const* d_in, const int* in_sizes, int n_in,
                              void* d_out, int out_size, void* d_ws, size_t ws_size,
                              hipStream_t stream) {
  const float* xs   = (const float*)d_in[0];
  const float* W    = (const float*)d_in[1];
  const float* bias = (const float*)d_in[2];
  float* out = (float*)d_out;
  char*  ws  = (char*)d_ws;

  const size_t XP_OFF = 0;                       // bf16 x_proj (T,B,H): 256 MiB
  const size_t HB_OFF = 268435456;               // bf16 h double-buffer: 1 MiB
  const size_t BR_OFF = HB_OFF + 1048576;        // barrier flags: 8 KiB
  const size_t NEED   = BR_OFF + 8192;
  if (ws_size < NEED) {
    hipMemsetAsync(d_out, 0, (size_t)out_size * 4, stream);
    return;
  }

  ushort* xp    = (ushort*)(ws + XP_OFF);
  ushort* hb    = (ushort*)(ws + HB_OFF);
  int*    flags = (int*)(ws + BR_OFF);

  // barrier flags must be fresh every call (ws not re-poisoned between replays)
  hipMemsetAsync(flags, 0, 128 * 16 * sizeof(int), stream);

  xproj_gemm<<<8192, 256, 0, stream>>>(xs, W, bias, xp);
  rnn_scan<<<128, 256, 0, stream>>>(W, xp, hb, out, flags);
}

// Round 3
// 4451.924 us; speedup vs baseline: 2.4761x; 1.2990x over previous
//
#include <hip/hip_runtime.h>
#include <hip/hip_bf16.h>
#include <stdint.h>

#define B_  256
#define T_  512
#define H_  1024
#define BH  (B_ * H_)

typedef float  f32x4  __attribute__((ext_vector_type(4)));
typedef __bf16 bf16x8 __attribute__((ext_vector_type(8)));
typedef unsigned long long u64;

__device__ inline ushort f2bf(float f) {
  union { float f; uint32_t u; } v; v.f = f;
  uint32_t u = v.u;
  return (ushort)((u + 0x7fffu + ((u >> 16) & 1u)) >> 16);   // RNE
}
__device__ inline float bf2f(ushort h) {
  union { uint32_t u; float f; } v; v.u = ((uint32_t)h) << 16;
  return v.f;
}
__device__ inline bf16x8 ld_bf8(const ushort* p) {
  union { uint4 u; bf16x8 b; } v;
  v.u = *(const uint4*)p;
  return v.b;
}
__device__ inline bf16x8 as_bf8(uint4 u) {
  union { uint4 a; bf16x8 b; } v; v.a = u; return v.b;
}
// coherent (device-scope) 16B load, UNTRACKED: caller must s_waitcnt vmcnt
// before reading the result. Issues pipeline freely (no per-load drain).
__device__ inline uint4 ld16_sc1(const ushort* p) {
  uint4 r;
  asm volatile("global_load_dwordx4 %0, %1, off sc1" : "=&v"(r) : "v"(p));
  return r;
}
// plain cached 2B load, untracked (prefetch path)
__device__ inline uint32_t ld2_pf(const ushort* p) {
  uint32_t r;
  asm volatile("global_load_ushort %0, %1, off" : "=&v"(r) : "v"(p));
  return r;
}
// device-scope 2B store (to coherence point)
__device__ inline void st_bf_coh(ushort* p, ushort v) {
  asm volatile("global_store_short %0, %1, off sc1" :: "v"(p), "v"((uint32_t)v) : "memory");
}
__device__ inline float tanh_fast(float x) {
  float xc = fminf(fmaxf(x, -15.f), 15.f);
  float e  = __expf(2.f * xc);
  return (e - 1.f) * __builtin_amdgcn_rcpf(e + 1.f);
}

// ------------------------------------------------- x_proj = xs @ Wx^T + bias
// bid mapping: nt inner (8 wide) so the xs panel is fetched ~once from HBM
// (concurrent nt-blocks share it via L3). Output bf16 in (T, B, H) layout.
__global__ __launch_bounds__(256) void xproj_gemm(const float* __restrict__ xs,
                                                  const float* __restrict__ W,
                                                  const float* __restrict__ bias,
                                                  ushort* __restrict__ xp) {
  __shared__ ushort As[128 * 32];
  __shared__ ushort Bs[128 * 32];
  const int bid = blockIdx.x;
  const int mt = bid >> 3, nt = bid & 7;
  const int tid = threadIdx.x;
  const int lane = tid & 63, wid = tid >> 6;
  const int wr = wid >> 1, wc = wid & 1;
  const int lr = lane & 15, lq = lane >> 4;

  const int srow = tid >> 1, scol = (tid & 1) * 16;
  const float* ag = xs + (size_t)(mt * 128 + srow) * 1024 + scol;
  const float* bg = W  + (size_t)(nt * 128 + srow) * 2048 + scol;
  ushort* as = As + srow * 32 + scol;
  ushort* bs = Bs + srow * 32 + scol;

  f32x4 acc[4][4];
#pragma unroll
  for (int m = 0; m < 4; ++m)
#pragma unroll
    for (int n = 0; n < 4; ++n) acc[m][n] = (f32x4){0.f, 0.f, 0.f, 0.f};

  for (int kc = 0; kc < 32; ++kc) {
    float4 a0 = *(const float4*)(ag + kc * 32);
    float4 a1 = *(const float4*)(ag + kc * 32 + 4);
    float4 a2 = *(const float4*)(ag + kc * 32 + 8);
    float4 a3 = *(const float4*)(ag + kc * 32 + 12);
    float4 b0 = *(const float4*)(bg + kc * 32);
    float4 b1 = *(const float4*)(bg + kc * 32 + 4);
    float4 b2 = *(const float4*)(bg + kc * 32 + 8);
    float4 b3 = *(const float4*)(bg + kc * 32 + 12);
    __syncthreads();
    {
      ushort t[16] = { f2bf(a0.x), f2bf(a0.y), f2bf(a0.z), f2bf(a0.w),
                       f2bf(a1.x), f2bf(a1.y), f2bf(a1.z), f2bf(a1.w),
                       f2bf(a2.x), f2bf(a2.y), f2bf(a2.z), f2bf(a2.w),
                       f2bf(a3.x), f2bf(a3.y), f2bf(a3.z), f2bf(a3.w) };
      *(uint4*)as       = *(const uint4*)t;
      *(uint4*)(as + 8) = *(const uint4*)(t + 8);
      ushort u[16] = { f2bf(b0.x), f2bf(b0.y), f2bf(b0.z), f2bf(b0.w),
                       f2bf(b1.x), f2bf(b1.y), f2bf(b1.z), f2bf(b1.w),
                       f2bf(b2.x), f2bf(b2.y), f2bf(b2.z), f2bf(b2.w),
                       f2bf(b3.x), f2bf(b3.y), f2bf(b3.z), f2bf(b3.w) };
      *(uint4*)bs       = *(const uint4*)u;
      *(uint4*)(bs + 8) = *(const uint4*)(u + 8);
    }
    __syncthreads();
    bf16x8 af[4], bfv[4];
#pragma unroll
    for (int m = 0; m < 4; ++m)
      af[m] = ld_bf8(As + (wr * 64 + m * 16 + lr) * 32 + lq * 8);
#pragma unroll
    for (int n = 0; n < 4; ++n)
      bfv[n] = ld_bf8(Bs + (wc * 64 + n * 16 + lr) * 32 + lq * 8);
#pragma unroll
    for (int m = 0; m < 4; ++m)
#pragma unroll
      for (int n = 0; n < 4; ++n)
        acc[m][n] = __builtin_amdgcn_mfma_f32_16x16x32_bf16(af[m], bfv[n], acc[m][n], 0, 0, 0);
  }

#pragma unroll
  for (int n = 0; n < 4; ++n) {
    int gn = nt * 128 + wc * 64 + n * 16 + lr;
    float bv = bias[gn];
#pragma unroll
    for (int m = 0; m < 4; ++m) {
      int gmb = mt * 128 + wr * 64 + m * 16 + lq * 4;
#pragma unroll
      for (int r = 0; r < 4; ++r) {
        int gm = gmb + r;
        int bi = gm >> 9, ti = gm & 511;     // m = b*512 + t
        xp[((size_t)ti * B_ + bi) * H_ + gn] = f2bf(acc[m][n][r] + bv);
      }
    }
  }
}

// ----------------------------------------------------------- persistent scan
// 128 wgs x 256 thr (4 waves). wg tile = 64 batch-rows x 32 H-cols.
// Row-groups of 32 wgs (sharing the same 64 batch rows) sync independently —
// batch rows are independent, so no global barrier is needed.
// Wh col-slice in LDS (staged once, XOR-swizzled). h exchanged via sc1 ops:
// untracked asm loads (all 32 chunks in flight, ONE vmcnt) + sc1 stores.
__global__ __launch_bounds__(256) void rnn_scan(const float* __restrict__ W,
                                                const ushort* __restrict__ xp,
                                                ushort* __restrict__ hb,
                                                float* __restrict__ out,
                                                int* __restrict__ flags) {
  __shared__ ushort Bsm[32 * 1024];          // 64 KB: Wh cols [ct*32, +32)
  const int bid = blockIdx.x, tid = threadIdx.x;
  const int rt = bid & 3, ct = bid >> 2;     // 4 row-tiles x 32 col-tiles
  const int lane = tid & 63, wid = tid >> 6;
  const int lr = lane & 15, lq = lane >> 4;
  const int rbase = rt * 64 + wid * 16;
  int* gflag = flags + (rt * 32 + ct) * 16;  // this wg's flag
  int* gpoll = flags + (rt * 32 + tid) * 16; // tid<32: flags of my row-group

  // ---- one-time stage: Wh (fp32, W[:,1024:]) -> bf16 LDS, 16B-granule swizzle
  {
    const int c  = tid >> 3;                 // 0..31  (local col)
    const int qb = (tid & 7) * 16;           // 16 x 16B chunks per thread
    const float* src = W + (size_t)(ct * 32 + c) * 2048 + 1024;
    char* dst = (char*)Bsm + c * 2048;
    const int sw = (c & 7) << 4;
#pragma unroll
    for (int q = qb; q < qb + 16; ++q) {
      float4 f0 = *(const float4*)(src + q * 8);
      float4 f1 = *(const float4*)(src + q * 8 + 4);
      ushort t[8] = { f2bf(f0.x), f2bf(f0.y), f2bf(f0.z), f2bf(f0.w),
                      f2bf(f1.x), f2bf(f1.y), f2bf(f1.z), f2bf(f1.w) };
      *(uint4*)(dst + ((q * 16) ^ sw)) = *(const uint4*)t;
    }
  }
  __syncthreads();

  const int gc0 = ct * 32 + lr;              // global col of frag 0 (frag1: +16)
  const int swz = (lr & 7) << 4;
  const int kb  = lq * 16;                   // lane's k-subgroup byte offset
  const char* bp0 = (char*)Bsm + lr * 2048;
  const char* bp1 = (char*)Bsm + (16 + lr) * 2048;

  uint32_t xv[8];                            // next step's xp slice (prefetch)

  // ---- step 0: h1 = tanh(xp[0])   (h0 == 0); then prefetch xp[1]
#pragma unroll
  for (int r = 0; r < 4; ++r) {
    int gr = rbase + lq * 4 + r;
    float v0 = tanh_fast(bf2f(xp[(size_t)gr * H_ + gc0]));
    float v1 = tanh_fast(bf2f(xp[(size_t)gr * H_ + gc0 + 16]));
    st_bf_coh(hb + (size_t)gr * H_ + gc0,      f2bf(v0));
    st_bf_coh(hb + (size_t)gr * H_ + gc0 + 16, f2bf(v1));
  }
#pragma unroll
  for (int r = 0; r < 4; ++r) {
    int gr = rbase + lq * 4 + r;
    xv[r]     = ld2_pf(xp + (size_t)BH + (size_t)gr * H_ + gc0);
    xv[r + 4] = ld2_pf(xp + (size_t)BH + (size_t)gr * H_ + gc0 + 16);
  }
  asm volatile("s_waitcnt vmcnt(8)" ::: "memory");   // stores drained
  __syncthreads();
  if (tid == 0)
    __hip_atomic_store(gflag, 1, __ATOMIC_RELAXED, __HIP_MEMORY_SCOPE_AGENT);
  if (tid < 32) {
    while (__hip_atomic_load(gpoll, __ATOMIC_RELAXED, __HIP_MEMORY_SCOPE_AGENT) < 1) {}
  }
  __syncthreads();

  for (int s = 1; s < T_; ++s) {
    const ushort* hprev = hb + ((s + 1) & 1) * BH;
    ushort*       hnext = hb + (s & 1) * BH;
    const ushort* arow  = hprev + (size_t)(rbase + lr) * H_ + lq * 8;

    // issue ALL 32 A-chunk loads (coherent, untracked) -> one L3 round trip
    uint4 A[32];
#pragma unroll
    for (int c = 0; c < 32; ++c) A[c] = ld16_sc1(arow + c * 32);
    asm volatile("s_waitcnt vmcnt(0)" ::: "memory");
    __builtin_amdgcn_sched_barrier(0);

    // 4 accumulator chains (depth 16 each)
    f32x4 a0a = {0,0,0,0}, a0b = {0,0,0,0}, a1a = {0,0,0,0}, a1b = {0,0,0,0};
#pragma unroll
    for (int c = 0; c < 32; ++c) {
      const int off = ((c << 6) | kb) ^ swz;
      bf16x8 b0 = *(const bf16x8*)(bp0 + off);
      bf16x8 b1 = *(const bf16x8*)(bp1 + off);
      bf16x8 av = as_bf8(A[c]);
      if (c & 1) {
        a0b = __builtin_amdgcn_mfma_f32_16x16x32_bf16(av, b0, a0b, 0, 0, 0);
        a1b = __builtin_amdgcn_mfma_f32_16x16x32_bf16(av, b1, a1b, 0, 0, 0);
      } else {
        a0a = __builtin_amdgcn_mfma_f32_16x16x32_bf16(av, b0, a0a, 0, 0, 0);
        a1a = __builtin_amdgcn_mfma_f32_16x16x32_bf16(av, b1, a1a, 0, 0, 0);
      }
    }
    f32x4 acc0 = a0a + a0b, acc1 = a1a + a1b;

    if (s < T_ - 1) {
#pragma unroll
      for (int r = 0; r < 4; ++r) {
        int gr = rbase + lq * 4 + r;
        float v0 = tanh_fast(acc0[r] + bf2f((ushort)xv[r]));
        float v1 = tanh_fast(acc1[r] + bf2f((ushort)xv[r + 4]));
        st_bf_coh(hnext + (size_t)gr * H_ + gc0,      f2bf(v0));
        st_bf_coh(hnext + (size_t)gr * H_ + gc0 + 16, f2bf(v1));
      }
      // prefetch next step's xp slice (hides HBM latency under the barrier)
      const ushort* xnext = xp + (size_t)(s + 1) * BH;
#pragma unroll
      for (int r = 0; r < 4; ++r) {
        int gr = rbase + lq * 4 + r;
        xv[r]     = ld2_pf(xnext + (size_t)gr * H_ + gc0);
        xv[r + 4] = ld2_pf(xnext + (size_t)gr * H_ + gc0 + 16);
      }
      asm volatile("s_waitcnt vmcnt(8)" ::: "memory");   // 8 stores retired
      __syncthreads();
      if (tid == 0)
        __hip_atomic_store(gflag, s + 1, __ATOMIC_RELAXED, __HIP_MEMORY_SCOPE_AGENT);
      if (tid < 32) {
        while (__hip_atomic_load(gpoll, __ATOMIC_RELAXED, __HIP_MEMORY_SCOPE_AGENT) < s + 1) {}
      }
      __syncthreads();
    } else {
#pragma unroll
      for (int r = 0; r < 4; ++r) {
        int gr = rbase + lq * 4 + r;
        float v0 = tanh_fast(acc0[r] + bf2f((ushort)xv[r]));
        float v1 = tanh_fast(acc1[r] + bf2f((ushort)xv[r + 4]));
        out[(size_t)gr * H_ + gc0]                   = v0;
        out[(size_t)gr * H_ + gc0 + 16]              = v1;
        out[(size_t)BH + (size_t)gr * H_ + gc0]      = v0;
        out[(size_t)BH + (size_t)gr * H_ + gc0 + 16] = v1;
      }
    }
  }
}

// ---------------------------------------------------------------------- host
extern "C" void kernel_launch(void* const* d_in, const int* in_sizes, int n_in,
                              void* d_out, int out_size, void* d_ws, size_t ws_size,
                              hipStream_t stream) {
  const float* xs   = (const float*)d_in[0];
  const float* W    = (const float*)d_in[1];
  const float* bias = (const float*)d_in[2];
  float* out = (float*)d_out;
  char*  ws  = (char*)d_ws;

  const size_t XP_OFF = 0;                       // bf16 x_proj (T,B,H): 256 MiB
  const size_t HB_OFF = 268435456;               // bf16 h double-buffer: 1 MiB
  const size_t BR_OFF = HB_OFF + 1048576;        // barrier flags: 8 KiB
  const size_t NEED   = BR_OFF + 8192;
  if (ws_size < NEED) {
    hipMemsetAsync(d_out, 0, (size_t)out_size * 4, stream);
    return;
  }

  ushort* xp    = (ushort*)(ws + XP_OFF);
  ushort* hb    = (ushort*)(ws + HB_OFF);
  int*    flags = (int*)(ws + BR_OFF);

  // barrier flags must be fresh every call (ws not re-poisoned between replays)
  hipMemsetAsync(flags, 0, 128 * 16 * sizeof(int), stream);

  xproj_gemm<<<8192, 256, 0, stream>>>(xs, W, bias, xp);
  rnn_scan<<<128, 256, 0, stream>>>(W, xp, hb, out, flags);
}

// Round 5
// 4059.361 us; speedup vs baseline: 2.7156x; 1.0967x over previous
//
#include <hip/hip_runtime.h>
#include <hip/hip_bf16.h>
#include <stdint.h>

#define B_  256
#define T_  512
#define H_  1024
#define BH  (B_ * H_)

typedef float  f32x4  __attribute__((ext_vector_type(4)));
typedef __bf16 bf16x8 __attribute__((ext_vector_type(8)));

__device__ inline ushort f2bf(float f) {
  union { float f; uint32_t u; } v; v.f = f;
  uint32_t u = v.u;
  return (ushort)((u + 0x7fffu + ((u >> 16) & 1u)) >> 16);   // RNE
}
__device__ inline float bf2f(ushort h) {
  union { uint32_t u; float f; } v; v.u = ((uint32_t)h) << 16;
  return v.f;
}
__device__ inline bf16x8 ld_bf8(const ushort* p) {
  union { uint4 u; bf16x8 b; } v;
  v.u = *(const uint4*)p;
  return v.b;
}
__device__ inline bf16x8 as_bf8(uint4 u) {
  union { uint4 a; bf16x8 b; } v; v.a = u; return v.b;
}
// coherent (device-scope) 16B load, UNTRACKED: caller must s_waitcnt vmcnt.
__device__ inline uint4 ld16_sc1(const ushort* p) {
  uint4 r;
  asm volatile("global_load_dwordx4 %0, %1, off sc1" : "=&v"(r) : "v"(p));
  return r;
}
// plain cached 2B load, untracked (xp prefetch)
__device__ inline uint32_t ld2_pf(const ushort* p) {
  uint32_t r;
  asm volatile("global_load_ushort %0, %1, off" : "=&v"(r) : "v"(p));
  return r;
}
// device-scope 2B store (to coherence point)
__device__ inline void st_bf_coh(ushort* p, ushort v) {
  asm volatile("global_store_short %0, %1, off sc1" :: "v"(p), "v"((uint32_t)v) : "memory");
}
__device__ inline float tanh_fast(float x) {
  float xc = fminf(fmaxf(x, -15.f), 15.f);
  float e  = __expf(2.f * xc);
  return (e - 1.f) * __builtin_amdgcn_rcpf(e + 1.f);
}

// ------------------------------------------------- x_proj = xs @ Wx^T + bias
// (unchanged — passed r2/r3). Output bf16 in (T, B, H) layout.
__global__ __launch_bounds__(256) void xproj_gemm(const float* __restrict__ xs,
                                                  const float* __restrict__ W,
                                                  const float* __restrict__ bias,
                                                  ushort* __restrict__ xp) {
  __shared__ ushort As[128 * 32];
  __shared__ ushort Bs[128 * 32];
  const int bid = blockIdx.x;
  const int mt = bid >> 3, nt = bid & 7;
  const int tid = threadIdx.x;
  const int lane = tid & 63, wid = tid >> 6;
  const int wr = wid >> 1, wc = wid & 1;
  const int lr = lane & 15, lq = lane >> 4;

  const int srow = tid >> 1, scol = (tid & 1) * 16;
  const float* ag = xs + (size_t)(mt * 128 + srow) * 1024 + scol;
  const float* bg = W  + (size_t)(nt * 128 + srow) * 2048 + scol;
  ushort* as = As + srow * 32 + scol;
  ushort* bs = Bs + srow * 32 + scol;

  f32x4 acc[4][4];
#pragma unroll
  for (int m = 0; m < 4; ++m)
#pragma unroll
    for (int n = 0; n < 4; ++n) acc[m][n] = (f32x4){0.f, 0.f, 0.f, 0.f};

  for (int kc = 0; kc < 32; ++kc) {
    float4 a0 = *(const float4*)(ag + kc * 32);
    float4 a1 = *(const float4*)(ag + kc * 32 + 4);
    float4 a2 = *(const float4*)(ag + kc * 32 + 8);
    float4 a3 = *(const float4*)(ag + kc * 32 + 12);
    float4 b0 = *(const float4*)(bg + kc * 32);
    float4 b1 = *(const float4*)(bg + kc * 32 + 4);
    float4 b2 = *(const float4*)(bg + kc * 32 + 8);
    float4 b3 = *(const float4*)(bg + kc * 32 + 12);
    __syncthreads();
    {
      ushort t[16] = { f2bf(a0.x), f2bf(a0.y), f2bf(a0.z), f2bf(a0.w),
                       f2bf(a1.x), f2bf(a1.y), f2bf(a1.z), f2bf(a1.w),
                       f2bf(a2.x), f2bf(a2.y), f2bf(a2.z), f2bf(a2.w),
                       f2bf(a3.x), f2bf(a3.y), f2bf(a3.z), f2bf(a3.w) };
      *(uint4*)as       = *(const uint4*)t;
      *(uint4*)(as + 8) = *(const uint4*)(t + 8);
      ushort u[16] = { f2bf(b0.x), f2bf(b0.y), f2bf(b0.z), f2bf(b0.w),
                       f2bf(b1.x), f2bf(b1.y), f2bf(b1.z), f2bf(b1.w),
                       f2bf(b2.x), f2bf(b2.y), f2bf(b2.z), f2bf(b2.w),
                       f2bf(b3.x), f2bf(b3.y), f2bf(b3.z), f2bf(b3.w) };
      *(uint4*)bs       = *(const uint4*)u;
      *(uint4*)(bs + 8) = *(const uint4*)(u + 8);
    }
    __syncthreads();
    bf16x8 af[4], bfv[4];
#pragma unroll
    for (int m = 0; m < 4; ++m)
      af[m] = ld_bf8(As + (wr * 64 + m * 16 + lr) * 32 + lq * 8);
#pragma unroll
    for (int n = 0; n < 4; ++n)
      bfv[n] = ld_bf8(Bs + (wc * 64 + n * 16 + lr) * 32 + lq * 8);
#pragma unroll
    for (int m = 0; m < 4; ++m)
#pragma unroll
      for (int n = 0; n < 4; ++n)
        acc[m][n] = __builtin_amdgcn_mfma_f32_16x16x32_bf16(af[m], bfv[n], acc[m][n], 0, 0, 0);
  }

#pragma unroll
  for (int n = 0; n < 4; ++n) {
    int gn = nt * 128 + wc * 64 + n * 16 + lr;
    float bv = bias[gn];
#pragma unroll
    for (int m = 0; m < 4; ++m) {
      int gmb = mt * 128 + wr * 64 + m * 16 + lq * 4;
#pragma unroll
      for (int r = 0; r < 4; ++r) {
        int gm = gmb + r;
        int bi = gm >> 9, ti = gm & 511;     // m = b*512 + t
        xp[((size_t)ti * B_ + bi) * H_ + gn] = f2bf(acc[m][n][r] + bv);
      }
    }
  }
}

// ----------------------------------------------------------- persistent scan
// r3-proven structure. 128 wgs x 256 thr (4 waves). wg tile = 64 batch-rows
// x 32 H-cols; wave = 16 rows x 32 cols (2 MFMA chains), full K=1024.
// r5 deltas vs r3 (ONLY these):
//   1. Bsm declared 86 KiB (64 used) -> forces 1 wg/CU -> 128 active CUs,
//      per-CU coherent A-bytes halved (was 2 wgs/CU on 64 CUs).
//   2. A-batch wait split: vmcnt(16) -> MFMA chunks 0..15 -> vmcnt(0) ->
//      chunks 16..31 (overlap load tail with compute).
__global__ __launch_bounds__(256) void rnn_scan(const float* __restrict__ W,
                                                const ushort* __restrict__ xp,
                                                ushort* __restrict__ hb,
                                                float* __restrict__ out,
                                                int* __restrict__ flags) {
  __shared__ ushort Bsm[43 * 1024];          // 86 KB declared; 64 KB used (pad
                                             // forces 1 wg/CU occupancy)
  const int bid = blockIdx.x, tid = threadIdx.x;
  const int rt = bid & 3, ct = bid >> 2;     // 4 row-tiles x 32 col-tiles
  const int lane = tid & 63, wid = tid >> 6;
  const int lr = lane & 15, lq = lane >> 4;
  const int rbase = rt * 64 + wid * 16;

  // ---- one-time stage: Wh (fp32, W[:,1024:]) -> bf16 LDS, 16B-granule swizzle
  {
    const int c  = tid >> 3;                 // 0..31  (local col)
    const int qb = (tid & 7) * 16;           // 16 x 16B chunks per thread
    const float* src = W + (size_t)(ct * 32 + c) * 2048 + 1024;
    char* dst = (char*)Bsm + c * 2048;
    const int sw = (c & 7) << 4;
#pragma unroll
    for (int q = qb; q < qb + 16; ++q) {
      float4 f0 = *(const float4*)(src + q * 8);
      float4 f1 = *(const float4*)(src + q * 8 + 4);
      ushort t[8] = { f2bf(f0.x), f2bf(f0.y), f2bf(f0.z), f2bf(f0.w),
                      f2bf(f1.x), f2bf(f1.y), f2bf(f1.z), f2bf(f1.w) };
      *(uint4*)(dst + ((q * 16) ^ sw)) = *(const uint4*)t;
    }
  }
  __syncthreads();

  const int gc0 = ct * 32 + lr;              // global col of frag 0 (frag1: +16)
  const int swz = (lr & 7) << 4;
  const int kb  = lq * 16;                   // lane's k-subgroup byte offset
  const char* bp0 = (char*)Bsm + lr * 2048;
  const char* bp1 = (char*)Bsm + (16 + lr) * 2048;

  uint32_t xv[8];                            // next step's xp slice (prefetch)

  // ---- step 0: h1 = tanh(xp[0])   (h0 == 0); then prefetch xp[1]
#pragma unroll
  for (int r = 0; r < 4; ++r) {
    int gr = rbase + lq * 4 + r;
    float v0 = tanh_fast(bf2f(xp[(size_t)gr * H_ + gc0]));
    float v1 = tanh_fast(bf2f(xp[(size_t)gr * H_ + gc0 + 16]));
    st_bf_coh(hb + (size_t)gr * H_ + gc0,      f2bf(v0));
    st_bf_coh(hb + (size_t)gr * H_ + gc0 + 16, f2bf(v1));
  }
#pragma unroll
  for (int r = 0; r < 4; ++r) {
    int gr = rbase + lq * 4 + r;
    xv[r]     = ld2_pf(xp + (size_t)BH + (size_t)gr * H_ + gc0);
    xv[r + 4] = ld2_pf(xp + (size_t)BH + (size_t)gr * H_ + gc0 + 16);
  }
  asm volatile("s_waitcnt vmcnt(8)" ::: "memory");   // stores drained
  __syncthreads();
  if (tid == 0)
    __hip_atomic_store(flags + bid * 16, 1, __ATOMIC_RELAXED, __HIP_MEMORY_SCOPE_AGENT);
  if (tid < 32) {
    while (__hip_atomic_load(flags + (rt * 32 + tid) * 16, __ATOMIC_RELAXED,
                             __HIP_MEMORY_SCOPE_AGENT) < 1) {}
  }
  __syncthreads();

  for (int s = 1; s < T_; ++s) {
    const ushort* hprev = hb + ((s + 1) & 1) * BH;
    ushort*       hnext = hb + (s & 1) * BH;
    const ushort* arow  = hprev + (size_t)(rbase + lr) * H_ + lq * 8;

    // issue ALL 32 A-chunk loads (coherent, untracked)
    uint4 A[32];
#pragma unroll
    for (int c = 0; c < 32; ++c) A[c] = ld16_sc1(arow + c * 32);

    // first half ready (oldest 16+any stale pf drained); tail still in flight
    asm volatile("s_waitcnt vmcnt(16)" ::: "memory");
    __builtin_amdgcn_sched_barrier(0);

    f32x4 a0a = {0,0,0,0}, a0b = {0,0,0,0}, a1a = {0,0,0,0}, a1b = {0,0,0,0};
#pragma unroll
    for (int c = 0; c < 16; ++c) {
      const int off = ((c << 6) | kb) ^ swz;
      bf16x8 b0 = *(const bf16x8*)(bp0 + off);
      bf16x8 b1 = *(const bf16x8*)(bp1 + off);
      bf16x8 av = as_bf8(A[c]);
      if (c & 1) {
        a0b = __builtin_amdgcn_mfma_f32_16x16x32_bf16(av, b0, a0b, 0, 0, 0);
        a1b = __builtin_amdgcn_mfma_f32_16x16x32_bf16(av, b1, a1b, 0, 0, 0);
      } else {
        a0a = __builtin_amdgcn_mfma_f32_16x16x32_bf16(av, b0, a0a, 0, 0, 0);
        a1a = __builtin_amdgcn_mfma_f32_16x16x32_bf16(av, b1, a1a, 0, 0, 0);
      }
    }
    asm volatile("s_waitcnt vmcnt(0)" ::: "memory");
    __builtin_amdgcn_sched_barrier(0);
#pragma unroll
    for (int c = 16; c < 32; ++c) {
      const int off = ((c << 6) | kb) ^ swz;
      bf16x8 b0 = *(const bf16x8*)(bp0 + off);
      bf16x8 b1 = *(const bf16x8*)(bp1 + off);
      bf16x8 av = as_bf8(A[c]);
      if (c & 1) {
        a0b = __builtin_amdgcn_mfma_f32_16x16x32_bf16(av, b0, a0b, 0, 0, 0);
        a1b = __builtin_amdgcn_mfma_f32_16x16x32_bf16(av, b1, a1b, 0, 0, 0);
      } else {
        a0a = __builtin_amdgcn_mfma_f32_16x16x32_bf16(av, b0, a0a, 0, 0, 0);
        a1a = __builtin_amdgcn_mfma_f32_16x16x32_bf16(av, b1, a1a, 0, 0, 0);
      }
    }
    f32x4 acc0 = a0a + a0b, acc1 = a1a + a1b;

    if (s < T_ - 1) {
#pragma unroll
      for (int r = 0; r < 4; ++r) {
        int gr = rbase + lq * 4 + r;
        float v0 = tanh_fast(acc0[r] + bf2f((ushort)xv[r]));
        float v1 = tanh_fast(acc1[r] + bf2f((ushort)xv[r + 4]));
        st_bf_coh(hnext + (size_t)gr * H_ + gc0,      f2bf(v0));
        st_bf_coh(hnext + (size_t)gr * H_ + gc0 + 16, f2bf(v1));
      }
      // prefetch next step's xp slice (hides HBM latency under the barrier)
      const ushort* xnext = xp + (size_t)(s + 1) * BH;
#pragma unroll
      for (int r = 0; r < 4; ++r) {
        int gr = rbase + lq * 4 + r;
        xv[r]     = ld2_pf(xnext + (size_t)gr * H_ + gc0);
        xv[r + 4] = ld2_pf(xnext + (size_t)gr * H_ + gc0 + 16);
      }
      asm volatile("s_waitcnt vmcnt(8)" ::: "memory");   // 8 stores retired
      __syncthreads();
      if (tid == 0)
        __hip_atomic_store(flags + bid * 16, s + 1, __ATOMIC_RELAXED, __HIP_MEMORY_SCOPE_AGENT);
      if (tid < 32) {
        while (__hip_atomic_load(flags + (rt * 32 + tid) * 16, __ATOMIC_RELAXED,
                                 __HIP_MEMORY_SCOPE_AGENT) < s + 1) {}
      }
      __syncthreads();
    } else {
#pragma unroll
      for (int r = 0; r < 4; ++r) {
        int gr = rbase + lq * 4 + r;
        float v0 = tanh_fast(acc0[r] + bf2f((ushort)xv[r]));
        float v1 = tanh_fast(acc1[r] + bf2f((ushort)xv[r + 4]));
        out[(size_t)gr * H_ + gc0]                   = v0;
        out[(size_t)gr * H_ + gc0 + 16]              = v1;
        out[(size_t)BH + (size_t)gr * H_ + gc0]      = v0;
        out[(size_t)BH + (size_t)gr * H_ + gc0 + 16] = v1;
      }
    }
  }
}

// ---------------------------------------------------------------------- host
extern "C" void kernel_launch(void* const* d_in, const int* in_sizes, int n_in,
                              void* d_out, int out_size, void* d_ws, size_t ws_size,
                              hipStream_t stream) {
  const float* xs   = (const float*)d_in[0];
  const float* W    = (const float*)d_in[1];
  const float* bias = (const float*)d_in[2];
  float* out = (float*)d_out;
  char*  ws  = (char*)d_ws;

  const size_t XP_OFF = 0;                       // bf16 x_proj (T,B,H): 256 MiB
  const size_t HB_OFF = 268435456;               // bf16 h double-buffer: 1 MiB
  const size_t BR_OFF = HB_OFF + 1048576;        // barrier flags: 8 KiB
  const size_t NEED   = BR_OFF + 8192;
  if (ws_size < NEED) {
    hipMemsetAsync(d_out, 0, (size_t)out_size * 4, stream);
    return;
  }

  ushort* xp    = (ushort*)(ws + XP_OFF);
  ushort* hb    = (ushort*)(ws + HB_OFF);
  int*    flags = (int*)(ws + BR_OFF);

  // barrier flags must be fresh every call (ws not re-poisoned between replays)
  hipMemsetAsync(flags, 0, 128 * 16 * sizeof(int), stream);

  xproj_gemm<<<8192, 256, 0, stream>>>(xs, W, bias, xp);
  rnn_scan<<<128, 256, 0, stream>>>(W, xp, hb, out, flags);
}